// Round 1
// baseline (4408.552 us; speedup 1.0000x reference)
//
#include <hip/hip_runtime.h>

// Problem constants (match reference)
#define N_NODES  50000
#define N_EDGES  1600000
#define N_GRAPHS 1000
#define F_IN     92
#define WIDTH    128
#define F_OUT    64

// Workspace layout (in floats)
static const long long AGG1_OFF = 0;          // 50000*128 = 6,400,000
static const long long AGG2_OFF = 6400000;    // 50000*64  = 3,200,000
static const long long DEGO_OFF = 9600000;    // 50,000
static const long long DEGI_OFF = 9650000;    // 50,000
static const long long CNT_OFF  = 9700000;    // 1,000
static const long long ZERO_FLOATS = 9701000; // everything above must be zeroed
static const long long EW_OFF   = 9701000;    // 1,600,000
static const long long NSRC_OFF = 11301000;   // 50,000
static const long long NDST_OFF = 11351000;   // 50,000
static const long long HS1_OFF  = 11401000;   // 6,400,000
static const long long HS2_OFF  = 17801000;   // 3,200,000
// total = 21,001,000 floats = 84,004,000 bytes

// K1: edge weights + degree histogram
__global__ void k_edge_prep(const float* __restrict__ bl,
                            const int* __restrict__ src,
                            const int* __restrict__ dst,
                            float* __restrict__ ew,
                            float* __restrict__ deg_out,
                            float* __restrict__ deg_in) {
    int e = blockIdx.x * blockDim.x + threadIdx.x;
    if (e >= N_EDGES) return;
    float x = bl[3 * e + 0];
    float y = bl[3 * e + 1];
    float z = bl[3 * e + 2];
    float r2 = x * x + y * y + z * z;
    ew[e] = expf(-r2 * (1.0f / 64.0f));
    atomicAdd(&deg_out[src[e]], 1.0f);
    atomicAdd(&deg_in[dst[e]], 1.0f);
}

// K2: norms + per-graph node counts
__global__ void k_node_prep(const float* __restrict__ deg_out,
                            const float* __restrict__ deg_in,
                            const int* __restrict__ gid,
                            float* __restrict__ nsrc,
                            float* __restrict__ ndst,
                            float* __restrict__ cnt) {
    int i = blockIdx.x * blockDim.x + threadIdx.x;
    if (i >= N_NODES) return;
    nsrc[i] = 1.0f / sqrtf(fmaxf(deg_out[i], 1.0f));
    ndst[i] = 1.0f / sqrtf(fmaxf(deg_in[i], 1.0f));
    atomicAdd(&cnt[gid[i]], 1.0f);
}

// K3: hs1 = (atom_features @ W0 + b0) * nsrc     [8 rows per 128-thread block]
__global__ __launch_bounds__(128) void k_embed(const float* __restrict__ af,
                                               const float* __restrict__ W0,
                                               const float* __restrict__ b0,
                                               const float* __restrict__ nsrc,
                                               float* __restrict__ hs1) {
    __shared__ float tile[8 * F_IN];
    const int row0 = blockIdx.x * 8;
    const int tid = threadIdx.x;
    const float* base = af + (long long)row0 * F_IN;
    for (int i = tid; i < 8 * F_IN; i += 128) tile[i] = base[i];
    __syncthreads();
    float acc[8];
    const float bb = b0[tid];
#pragma unroll
    for (int r = 0; r < 8; ++r) acc[r] = bb;
    for (int k = 0; k < F_IN; ++k) {
        const float w = W0[k * WIDTH + tid];
#pragma unroll
        for (int r = 0; r < 8; ++r) acc[r] = fmaf(tile[r * F_IN + k], w, acc[r]);
    }
#pragma unroll
    for (int r = 0; r < 8; ++r)
        hs1[(long long)(row0 + r) * WIDTH + tid] = acc[r] * nsrc[row0 + r];
}

// K4: agg1[dst] += hs1[src] * ew   (edge-parallel, 32 threads/edge, float4 each)
__global__ void k_scatter1(const float* __restrict__ hs1,
                           const int* __restrict__ src,
                           const int* __restrict__ dst,
                           const float* __restrict__ ew,
                           float* __restrict__ agg1) {
    int idx = blockIdx.x * blockDim.x + threadIdx.x;  // N_EDGES*32 = 51.2M < 2^31
    int e = idx >> 5;
    if (e >= N_EDGES) return;
    int q = idx & 31;
    int s = src[e], d = dst[e];
    float w = ew[e];
    float4 h4 = reinterpret_cast<const float4*>(hs1)[(long long)s * 32 + q];
    float* ap = agg1 + (long long)d * WIDTH + q * 4;
    atomicAdd(ap + 0, h4.x * w);
    atomicAdd(ap + 1, h4.y * w);
    atomicAdd(ap + 2, h4.z * w);
    atomicAdd(ap + 3, h4.w * w);
}

// K5: x = relu((agg1*ndst) @ W1 + b1);  hs2 = (x*nsrc) @ W2   [8 rows / 128-thread block]
__global__ __launch_bounds__(128) void k_layer1(const float* __restrict__ agg1,
                                                const float* __restrict__ ndst,
                                                const float* __restrict__ W1,
                                                const float* __restrict__ b1,
                                                const float* __restrict__ nsrc,
                                                const float* __restrict__ W2,
                                                float* __restrict__ hs2) {
    __shared__ float a_t[8][WIDTH];
    __shared__ float x_t[8][WIDTH];
    const int row0 = blockIdx.x * 8;
    const int tid = threadIdx.x;
    for (int i = tid; i < 8 * WIDTH; i += 128) {
        int r = i >> 7, k = i & 127;
        a_t[r][k] = agg1[(long long)(row0 + r) * WIDTH + k] * ndst[row0 + r];
    }
    __syncthreads();
    float acc[8];
    const float bb = b1[tid];
#pragma unroll
    for (int r = 0; r < 8; ++r) acc[r] = bb;
    for (int k = 0; k < WIDTH; ++k) {
        const float w = W1[k * WIDTH + tid];
#pragma unroll
        for (int r = 0; r < 8; ++r) acc[r] = fmaf(a_t[r][k], w, acc[r]);
    }
#pragma unroll
    for (int r = 0; r < 8; ++r)
        x_t[r][tid] = fmaxf(acc[r], 0.0f) * nsrc[row0 + r];
    __syncthreads();
    // second GEMM: thread t -> col c2 = t&63, rows {rb, rb+2, rb+4, rb+6}, rb = t>>6
    const int c2 = tid & 63;
    const int rb = tid >> 6;
    float acc2[4] = {0.f, 0.f, 0.f, 0.f};
    for (int k = 0; k < WIDTH; ++k) {
        const float w = W2[k * F_OUT + c2];
#pragma unroll
        for (int j = 0; j < 4; ++j) acc2[j] = fmaf(x_t[rb + 2 * j][k], w, acc2[j]);
    }
#pragma unroll
    for (int j = 0; j < 4; ++j)
        hs2[(long long)(row0 + rb + 2 * j) * F_OUT + c2] = acc2[j];
}

// K6: agg2[dst] += hs2[src] * ew   (16 threads/edge, float4 each)
__global__ void k_scatter2(const float* __restrict__ hs2,
                           const int* __restrict__ src,
                           const int* __restrict__ dst,
                           const float* __restrict__ ew,
                           float* __restrict__ agg2) {
    int idx = blockIdx.x * blockDim.x + threadIdx.x;  // N_EDGES*16 = 25.6M
    int e = idx >> 4;
    if (e >= N_EDGES) return;
    int q = idx & 15;
    int s = src[e], d = dst[e];
    float w = ew[e];
    float4 h4 = reinterpret_cast<const float4*>(hs2)[(long long)s * 16 + q];
    float* ap = agg2 + (long long)d * F_OUT + q * 4;
    atomicAdd(ap + 0, h4.x * w);
    atomicAdd(ap + 1, h4.y * w);
    atomicAdd(ap + 2, h4.z * w);
    atomicAdd(ap + 3, h4.w * w);
}

// K7: per-node final value scattered into per-graph sums
__global__ void k_pool(const float* __restrict__ agg2,
                       const float* __restrict__ ndst,
                       const float* __restrict__ b2,
                       const int* __restrict__ gid,
                       float* __restrict__ out) {
    int idx = blockIdx.x * blockDim.x + threadIdx.x;  // N_NODES*64 = 3.2M
    if (idx >= N_NODES * F_OUT) return;
    int n = idx >> 6;
    int c = idx & 63;
    int g = gid[n];
    float val = agg2[(long long)n * F_OUT + c] * ndst[n] + b2[c];
    atomicAdd(&out[(long long)g * F_OUT + c], val);
}

// K8: divide per-graph sums by counts
__global__ void k_divide(float* __restrict__ out, const float* __restrict__ cnt) {
    int idx = blockIdx.x * blockDim.x + threadIdx.x;  // N_GRAPHS*64 = 64000
    if (idx >= N_GRAPHS * F_OUT) return;
    out[idx] = out[idx] / fmaxf(cnt[idx >> 6], 1.0f);
}

extern "C" void kernel_launch(void* const* d_in, const int* in_sizes, int n_in,
                              void* d_out, int out_size, void* d_ws, size_t ws_size,
                              hipStream_t stream) {
    const float* af  = (const float*)d_in[0];
    const float* bl  = (const float*)d_in[1];
    const int*   src = (const int*)d_in[2];
    const int*   dst = (const int*)d_in[3];
    const int*   gid = (const int*)d_in[4];
    const float* W0  = (const float*)d_in[5];
    const float* b0  = (const float*)d_in[6];
    const float* W1  = (const float*)d_in[7];
    const float* b1  = (const float*)d_in[8];
    const float* W2  = (const float*)d_in[9];
    const float* b2  = (const float*)d_in[10];
    float* out = (float*)d_out;
    float* ws  = (float*)d_ws;

    float* agg1 = ws + AGG1_OFF;
    float* agg2 = ws + AGG2_OFF;
    float* dego = ws + DEGO_OFF;
    float* degi = ws + DEGI_OFF;
    float* cnt  = ws + CNT_OFF;
    float* ew   = ws + EW_OFF;
    float* nsrc = ws + NSRC_OFF;
    float* ndst = ws + NDST_OFF;
    float* hs1  = ws + HS1_OFF;
    float* hs2  = ws + HS2_OFF;

    // zero accumulators (ws is poisoned 0xAA before every timed launch) + output
    hipMemsetAsync(d_ws, 0, (size_t)ZERO_FLOATS * sizeof(float), stream);
    hipMemsetAsync(d_out, 0, (size_t)N_GRAPHS * F_OUT * sizeof(float), stream);

    // K1: edge weights + degrees
    k_edge_prep<<<(N_EDGES + 255) / 256, 256, 0, stream>>>(bl, src, dst, ew, dego, degi);
    // K2: norms + graph counts
    k_node_prep<<<(N_NODES + 255) / 256, 256, 0, stream>>>(dego, degi, gid, nsrc, ndst, cnt);
    // K3: embedding GEMM (+ nsrc scale)
    k_embed<<<N_NODES / 8, 128, 0, stream>>>(af, W0, b0, nsrc, hs1);
    // K4: layer1 scatter
    k_scatter1<<<(N_EDGES * 32) / 256, 256, 0, stream>>>(hs1, src, dst, ew, agg1);
    // K5: layer1 dense + layer2 weight
    k_layer1<<<N_NODES / 8, 128, 0, stream>>>(agg1, ndst, W1, b1, nsrc, W2, hs2);
    // K6: layer2 scatter
    k_scatter2<<<(N_EDGES * 16) / 256, 256, 0, stream>>>(hs2, src, dst, ew, agg2);
    // K7: pool (sum)
    k_pool<<<(N_NODES * F_OUT + 255) / 256, 256, 0, stream>>>(agg2, ndst, b2, gid, out);
    // K8: divide by counts
    k_divide<<<(N_GRAPHS * F_OUT + 255) / 256, 256, 0, stream>>>(out, cnt);
}

// Round 2
// 649.451 us; speedup vs baseline: 6.7881x; 6.7881x over previous
//
#include <hip/hip_runtime.h>

#define N_NODES  50000
#define N_EDGES  1600000
#define N_GRAPHS 1000
#define F_IN     92
#define WIDTH    128
#define F_OUT    64
#define NBLK_SCAN 196   // ceil(50000/256)

// ---- workspace layout (4-byte element offsets) ----
// zeroed region: [CNT, DEGO) = 100000 elements (400 KB)
static const int CNT   = 0;         // 50000 u32  in-degree counts (zeroed)
static const int DEGO  = 50000;     // 50000 u32  out-degree counts (zeroed)
static const int ROWP  = 100000;    // 50001 i32  CSR row pointers (by dst)
static const int CURS  = 150004;    // 50000 i32  fill cursors
static const int BSUM  = 200004;    // 256   i32  scan block sums
static const int NSRC  = 200260;    // 50000 f32  out_deg^-0.5
static const int NDST  = 250260;    // 50000 f32  in_deg^-0.5
static const int CSRS  = 300260;    // 1.6M  i32  CSR src node ids
static const int CSRW  = 1900260;   // 1.6M  f32  CSR edge weights
static const int HS1   = 3500260;   // 6.4M  f32  (also reused as AGG2 later)
static const int AGG1  = 9900260;   // 6.4M  f32
static const int HS2   = 16300260;  // 3.2M  f32
static const int AGG2  = HS1;       // 3.2M  f32  (aliases HS1 — hs1 dead by then)
// total = 19,500,260 * 4 B = 78.0 MB

// K1: degree histograms (int atomics, 50K counters -> L2-friendly)
__global__ void k_count(const int* __restrict__ src, const int* __restrict__ dst,
                        unsigned* __restrict__ dego, unsigned* __restrict__ cnt_in) {
    int e = blockIdx.x * blockDim.x + threadIdx.x;
    if (e >= N_EDGES) return;
    atomicAdd(&dego[src[e]], 1u);
    atomicAdd(&cnt_in[dst[e]], 1u);
}

// K2a: per-block exclusive scan of cnt_in -> rowp (block-local) + block sums
__global__ __launch_bounds__(256) void k_scanA(const unsigned* __restrict__ cnt_in,
                                               int* __restrict__ rowp,
                                               int* __restrict__ bsum) {
    __shared__ int sd[256];
    const int t = threadIdx.x;
    const int i = blockIdx.x * 256 + t;
    int v = (i < N_NODES) ? (int)cnt_in[i] : 0;
    sd[t] = v;
    __syncthreads();
    for (int off = 1; off < 256; off <<= 1) {
        int add = (t >= off) ? sd[t - off] : 0;
        __syncthreads();
        sd[t] += add;
        __syncthreads();
    }
    if (i < N_NODES) rowp[i] = sd[t] - v;            // exclusive within block
    if (t == 255) bsum[blockIdx.x] = sd[255];
}

// K2b: exclusive scan of block sums (single block)
__global__ __launch_bounds__(256) void k_scanB(int* __restrict__ bsum) {
    __shared__ int sd[256];
    const int t = threadIdx.x;
    int v = (t < NBLK_SCAN) ? bsum[t] : 0;
    sd[t] = v;
    __syncthreads();
    for (int off = 1; off < 256; off <<= 1) {
        int add = (t >= off) ? sd[t - off] : 0;
        __syncthreads();
        sd[t] += add;
        __syncthreads();
    }
    if (t < NBLK_SCAN) bsum[t] = sd[t] - v;          // exclusive
}

// K2c: finalize row_ptr, init cursors, compute norms
__global__ void k_scanC(int* __restrict__ rowp, const int* __restrict__ bsum,
                        int* __restrict__ curs,
                        const unsigned* __restrict__ dego,
                        const unsigned* __restrict__ cnt_in,
                        float* __restrict__ nsrc, float* __restrict__ ndst) {
    int i = blockIdx.x * blockDim.x + threadIdx.x;
    if (i >= N_NODES) return;
    int rp = rowp[i] + bsum[i >> 8];
    rowp[i] = rp;
    curs[i] = rp;
    nsrc[i] = rsqrtf((float)max(dego[i], 1u));
    ndst[i] = rsqrtf((float)max(cnt_in[i], 1u));
    if (i == 0) rowp[N_NODES] = N_EDGES;
}

// K3: fill CSR (1.6M int atomics) + compute edge weights
__global__ void k_fill(const float* __restrict__ bl,
                       const int* __restrict__ src, const int* __restrict__ dst,
                       int* __restrict__ curs,
                       int* __restrict__ csr_src, float* __restrict__ csr_w) {
    int e = blockIdx.x * blockDim.x + threadIdx.x;
    if (e >= N_EDGES) return;
    float x = bl[3 * e + 0], y = bl[3 * e + 1], z = bl[3 * e + 2];
    float w = expf(-(x * x + y * y + z * z) * (1.0f / 64.0f));
    int p = atomicAdd(&curs[dst[e]], 1);
    csr_src[p] = src[e];
    csr_w[p] = w;
}

// K4: hs1 = (af @ W0 + b0) * nsrc    [8 rows per 128-thread block]
__global__ __launch_bounds__(128) void k_embed(const float* __restrict__ af,
                                               const float* __restrict__ W0,
                                               const float* __restrict__ b0,
                                               const float* __restrict__ nsrc,
                                               float* __restrict__ hs1) {
    __shared__ float tile[8 * F_IN];
    const int row0 = blockIdx.x * 8;
    const int tid = threadIdx.x;
    const float* base = af + row0 * F_IN;
    for (int i = tid; i < 8 * F_IN; i += 128) tile[i] = base[i];
    __syncthreads();
    float acc[8];
    const float bb = b0[tid];
#pragma unroll
    for (int r = 0; r < 8; ++r) acc[r] = bb;
    for (int k = 0; k < F_IN; ++k) {
        const float w = W0[k * WIDTH + tid];
#pragma unroll
        for (int r = 0; r < 8; ++r) acc[r] = fmaf(tile[r * F_IN + k], w, acc[r]);
    }
#pragma unroll
    for (int r = 0; r < 8; ++r)
        hs1[(row0 + r) * WIDTH + tid] = acc[r] * nsrc[row0 + r];
}

// K5: agg1[n] = sum over in-edges of hs1[src]*w   (block per node, 128 thr)
__global__ __launch_bounds__(128) void k_gather1(const int* __restrict__ rowp,
                                                 const int* __restrict__ csr_src,
                                                 const float* __restrict__ csr_w,
                                                 const float* __restrict__ hs1,
                                                 float* __restrict__ agg1) {
    __shared__ int s_s[128];
    __shared__ float s_w[128];
    const int n = blockIdx.x;
    const int tid = threadIdx.x;
    const int start = rowp[n], end = rowp[n + 1];
    float acc = 0.0f;
    for (int base = start; base < end; base += 128) {
        const int m = min(128, end - base);
        if (tid < m) { s_s[tid] = csr_src[base + tid]; s_w[tid] = csr_w[base + tid]; }
        __syncthreads();
        int j = 0;
        for (; j + 1 < m; j += 2) {
            float h0 = hs1[s_s[j] * WIDTH + tid];
            float h1 = hs1[s_s[j + 1] * WIDTH + tid];
            acc = fmaf(h0, s_w[j], acc);
            acc = fmaf(h1, s_w[j + 1], acc);
        }
        if (j < m) acc = fmaf(hs1[s_s[j] * WIDTH + tid], s_w[j], acc);
        __syncthreads();
    }
    agg1[n * WIDTH + tid] = acc;
}

// K6: x = relu((agg1*ndst) @ W1 + b1);  hs2 = (x*nsrc) @ W2
__global__ __launch_bounds__(128) void k_layer1(const float* __restrict__ agg1,
                                                const float* __restrict__ ndst,
                                                const float* __restrict__ W1,
                                                const float* __restrict__ b1,
                                                const float* __restrict__ nsrc,
                                                const float* __restrict__ W2,
                                                float* __restrict__ hs2) {
    __shared__ float a_t[8][WIDTH];
    __shared__ float x_t[8][WIDTH];
    const int row0 = blockIdx.x * 8;
    const int tid = threadIdx.x;
    for (int i = tid; i < 8 * WIDTH; i += 128) {
        int r = i >> 7, k = i & 127;
        a_t[r][k] = agg1[(row0 + r) * WIDTH + k] * ndst[row0 + r];
    }
    __syncthreads();
    float acc[8];
    const float bb = b1[tid];
#pragma unroll
    for (int r = 0; r < 8; ++r) acc[r] = bb;
    for (int k = 0; k < WIDTH; ++k) {
        const float w = W1[k * WIDTH + tid];
#pragma unroll
        for (int r = 0; r < 8; ++r) acc[r] = fmaf(a_t[r][k], w, acc[r]);
    }
#pragma unroll
    for (int r = 0; r < 8; ++r)
        x_t[r][tid] = fmaxf(acc[r], 0.0f) * nsrc[row0 + r];
    __syncthreads();
    const int c2 = tid & 63;
    const int rb = tid >> 6;
    float acc2[4] = {0.f, 0.f, 0.f, 0.f};
    for (int k = 0; k < WIDTH; ++k) {
        const float w = W2[k * F_OUT + c2];
#pragma unroll
        for (int j = 0; j < 4; ++j) acc2[j] = fmaf(x_t[rb + 2 * j][k], w, acc2[j]);
    }
#pragma unroll
    for (int j = 0; j < 4; ++j)
        hs2[(row0 + rb + 2 * j) * F_OUT + c2] = acc2[j];
}

// K7: agg2[n] = sum over in-edges of hs2[src]*w   (one wave per node)
__global__ __launch_bounds__(64) void k_gather2(const int* __restrict__ rowp,
                                                const int* __restrict__ csr_src,
                                                const float* __restrict__ csr_w,
                                                const float* __restrict__ hs2,
                                                float* __restrict__ agg2) {
    __shared__ int s_s[64];
    __shared__ float s_w[64];
    const int n = blockIdx.x;
    const int tid = threadIdx.x;
    const int start = rowp[n], end = rowp[n + 1];
    float acc = 0.0f;
    for (int base = start; base < end; base += 64) {
        const int m = min(64, end - base);
        if (tid < m) { s_s[tid] = csr_src[base + tid]; s_w[tid] = csr_w[base + tid]; }
        __syncthreads();
        int j = 0;
        for (; j + 1 < m; j += 2) {
            float h0 = hs2[s_s[j] * F_OUT + tid];
            float h1 = hs2[s_s[j + 1] * F_OUT + tid];
            acc = fmaf(h0, s_w[j], acc);
            acc = fmaf(h1, s_w[j + 1], acc);
        }
        if (j < m) acc = fmaf(hs2[s_s[j] * F_OUT + tid], s_w[j], acc);
        __syncthreads();
    }
    agg2[n * F_OUT + tid] = acc;
}

// K8: per-graph mean pooling via sorted-gid segments (binary search, no atomics)
__global__ __launch_bounds__(64) void k_pool(const float* __restrict__ agg2,
                                             const float* __restrict__ ndst,
                                             const float* __restrict__ b2,
                                             const int* __restrict__ gid,
                                             float* __restrict__ out) {
    const int g = blockIdx.x;
    const int t = threadIdx.x;
    // lower_bound(gid, g) and lower_bound(gid, g+1)
    int lo = 0, hi = N_NODES;
    while (lo < hi) { int mid = (lo + hi) >> 1; if (gid[mid] < g) lo = mid + 1; else hi = mid; }
    const int start = lo;
    hi = N_NODES;
    while (lo < hi) { int mid = (lo + hi) >> 1; if (gid[mid] < g + 1) lo = mid + 1; else hi = mid; }
    const int end = lo;
    float sum = 0.0f;
    for (int n = start; n < end; ++n)
        sum = fmaf(agg2[n * F_OUT + t], ndst[n], sum);
    out[g * F_OUT + t] = (end > start) ? (sum / (float)(end - start) + b2[t]) : 0.0f;
}

extern "C" void kernel_launch(void* const* d_in, const int* in_sizes, int n_in,
                              void* d_out, int out_size, void* d_ws, size_t ws_size,
                              hipStream_t stream) {
    const float* af  = (const float*)d_in[0];
    const float* bl  = (const float*)d_in[1];
    const int*   src = (const int*)d_in[2];
    const int*   dst = (const int*)d_in[3];
    const int*   gid = (const int*)d_in[4];
    const float* W0  = (const float*)d_in[5];
    const float* b0  = (const float*)d_in[6];
    const float* W1  = (const float*)d_in[7];
    const float* b1  = (const float*)d_in[8];
    const float* W2  = (const float*)d_in[9];
    const float* b2  = (const float*)d_in[10];
    float* out = (float*)d_out;
    float* ws  = (float*)d_ws;

    unsigned* cnt_in  = (unsigned*)(ws + CNT);
    unsigned* dego    = (unsigned*)(ws + DEGO);
    int*      rowp    = (int*)(ws + ROWP);
    int*      curs    = (int*)(ws + CURS);
    int*      bsum    = (int*)(ws + BSUM);
    float*    nsrc    = ws + NSRC;
    float*    ndst    = ws + NDST;
    int*      csr_src = (int*)(ws + CSRS);
    float*    csr_w   = ws + CSRW;
    float*    hs1     = ws + HS1;
    float*    agg1    = ws + AGG1;
    float*    hs2     = ws + HS2;
    float*    agg2    = ws + AGG2;   // aliases hs1 (dead by then)

    // zero only the degree counters (400 KB)
    hipMemsetAsync(d_ws, 0, 100000 * sizeof(float), stream);

    const int EB = (N_EDGES + 255) / 256;   // 6250
    k_count<<<EB, 256, 0, stream>>>(src, dst, dego, cnt_in);
    k_scanA<<<NBLK_SCAN, 256, 0, stream>>>(cnt_in, rowp, bsum);
    k_scanB<<<1, 256, 0, stream>>>(bsum);
    k_scanC<<<NBLK_SCAN, 256, 0, stream>>>(rowp, bsum, curs, dego, cnt_in, nsrc, ndst);
    k_fill<<<EB, 256, 0, stream>>>(bl, src, dst, curs, csr_src, csr_w);
    k_embed<<<N_NODES / 8, 128, 0, stream>>>(af, W0, b0, nsrc, hs1);
    k_gather1<<<N_NODES, 128, 0, stream>>>(rowp, csr_src, csr_w, hs1, agg1);
    k_layer1<<<N_NODES / 8, 128, 0, stream>>>(agg1, ndst, W1, b1, nsrc, W2, hs2);
    k_gather2<<<N_NODES, 64, 0, stream>>>(rowp, csr_src, csr_w, hs2, agg2);
    k_pool<<<N_GRAPHS, 64, 0, stream>>>(agg2, ndst, b2, gid, out);
}

// Round 3
// 526.013 us; speedup vs baseline: 8.3811x; 1.2347x over previous
//
#include <hip/hip_runtime.h>

#define N_NODES  50000
#define N_EDGES  1600000
#define N_GRAPHS 1000
#define F_IN     92
#define WIDTH    128
#define F_OUT    64
#define NBLK_SCAN 196   // ceil(50000/256)

// ---- workspace layout (4-byte element offsets) ----
// zeroed region: first 100000 elements (400 KB)
static const int CNT   = 0;         // 50000 u32  in-degree counts (zeroed)
static const int DEGO  = 50000;     // 50000 u32  out-degree counts (zeroed)
static const int ROWP  = 100000;    // 50001 i32  CSR row pointers (by dst)
static const int BSUM  = 150004;    // 256   i32  scan block sums
static const int NSRC  = 150260;    // 50000 f32
static const int NDST  = 200260;    // 50000 f32
static const int RANK  = 250260;    // 1.6M  i32  per-edge rank within dst
static const int CSRS  = 1850260;   // 1.6M  i32  CSR src ids
static const int CSRW  = 3450260;   // 1.6M  f32  CSR edge weights
static const int HS1   = 5050260;   // 50000*128 bf16 = 3.2M f32 slots
static const int AGG1  = 8250260;   // 6.4M  f32
static const int HS2   = 14650260;  // 50000*64 bf16 = 1.6M f32 slots
static const int AGG2  = HS1;       // 3.2M f32 (aliases HS1 — dead by then)
// total = 16,250,260 * 4 B = 65.0 MB

__device__ inline unsigned short f2bf(float f) {
    unsigned u = __float_as_uint(f);
    return (unsigned short)((u + 0x7fff + ((u >> 16) & 1)) >> 16);  // RN
}
__device__ inline float bflo(unsigned u) { return __uint_as_float(u << 16); }
__device__ inline float bfhi(unsigned u) { return __uint_as_float(u & 0xffff0000u); }

// K1: degree histograms; in-degree atomic's return value = edge rank within dst
__global__ void k_count(const int* __restrict__ src, const int* __restrict__ dst,
                        unsigned* __restrict__ dego, unsigned* __restrict__ cnt_in,
                        int* __restrict__ rank) {
    int e = blockIdx.x * blockDim.x + threadIdx.x;
    if (e >= N_EDGES) return;
    atomicAdd(&dego[src[e]], 1u);
    rank[e] = (int)atomicAdd(&cnt_in[dst[e]], 1u);
}

// K2a: per-block exclusive scan of cnt_in -> rowp (block-local) + block sums
__global__ __launch_bounds__(256) void k_scanA(const unsigned* __restrict__ cnt_in,
                                               int* __restrict__ rowp,
                                               int* __restrict__ bsum) {
    __shared__ int sd[256];
    const int t = threadIdx.x;
    const int i = blockIdx.x * 256 + t;
    int v = (i < N_NODES) ? (int)cnt_in[i] : 0;
    sd[t] = v;
    __syncthreads();
    for (int off = 1; off < 256; off <<= 1) {
        int add = (t >= off) ? sd[t - off] : 0;
        __syncthreads();
        sd[t] += add;
        __syncthreads();
    }
    if (i < N_NODES) rowp[i] = sd[t] - v;
    if (t == 255) bsum[blockIdx.x] = sd[255];
}

// K2b: exclusive scan of block sums (single block)
__global__ __launch_bounds__(256) void k_scanB(int* __restrict__ bsum) {
    __shared__ int sd[256];
    const int t = threadIdx.x;
    int v = (t < NBLK_SCAN) ? bsum[t] : 0;
    sd[t] = v;
    __syncthreads();
    for (int off = 1; off < 256; off <<= 1) {
        int add = (t >= off) ? sd[t - off] : 0;
        __syncthreads();
        sd[t] += add;
        __syncthreads();
    }
    if (t < NBLK_SCAN) bsum[t] = sd[t] - v;
}

// K2c: finalize row_ptr + norms
__global__ void k_scanC(int* __restrict__ rowp, const int* __restrict__ bsum,
                        const unsigned* __restrict__ dego,
                        const unsigned* __restrict__ cnt_in,
                        float* __restrict__ nsrc, float* __restrict__ ndst) {
    int i = blockIdx.x * blockDim.x + threadIdx.x;
    if (i >= N_NODES) return;
    rowp[i] = rowp[i] + bsum[i >> 8];
    nsrc[i] = rsqrtf((float)max(dego[i], 1u));
    ndst[i] = rsqrtf((float)max(cnt_in[i], 1u));
    if (i == 0) rowp[N_NODES] = N_EDGES;
}

// K3: fill CSR — NO atomics (p = rowp[dst] + rank)
__global__ void k_fill(const float* __restrict__ bl,
                       const int* __restrict__ src, const int* __restrict__ dst,
                       const int* __restrict__ rank, const int* __restrict__ rowp,
                       int* __restrict__ csr_src, float* __restrict__ csr_w) {
    int e = blockIdx.x * blockDim.x + threadIdx.x;
    if (e >= N_EDGES) return;
    float x = bl[3 * e + 0], y = bl[3 * e + 1], z = bl[3 * e + 2];
    float w = expf(-(x * x + y * y + z * z) * (1.0f / 64.0f));
    int p = rowp[dst[e]] + rank[e];
    csr_src[p] = src[e];
    csr_w[p] = w;
}

// K4: hs1 = bf16((af @ W0 + b0) * nsrc)
__global__ __launch_bounds__(128) void k_embed(const float* __restrict__ af,
                                               const float* __restrict__ W0,
                                               const float* __restrict__ b0,
                                               const float* __restrict__ nsrc,
                                               unsigned short* __restrict__ hs1h) {
    __shared__ float tile[8 * F_IN];
    const int row0 = blockIdx.x * 8;
    const int tid = threadIdx.x;
    const float* base = af + row0 * F_IN;
    for (int i = tid; i < 8 * F_IN; i += 128) tile[i] = base[i];
    __syncthreads();
    float acc[8];
    const float bb = b0[tid];
#pragma unroll
    for (int r = 0; r < 8; ++r) acc[r] = bb;
    for (int k = 0; k < F_IN; ++k) {
        const float w = W0[k * WIDTH + tid];
#pragma unroll
        for (int r = 0; r < 8; ++r) acc[r] = fmaf(tile[r * F_IN + k], w, acc[r]);
    }
#pragma unroll
    for (int r = 0; r < 8; ++r)
        hs1h[(row0 + r) * WIDTH + tid] = f2bf(acc[r] * nsrc[row0 + r]);
}

// K5: agg1[n] = sum_in-edges hs1[src]*w   (1 wave per node, bf16x2 per lane)
__global__ __launch_bounds__(64) void k_gather1(const int* __restrict__ rowp,
                                                const int* __restrict__ csr_src,
                                                const float* __restrict__ csr_w,
                                                const unsigned* __restrict__ hs1u,
                                                float2* __restrict__ agg1f2) {
    __shared__ int s_s[64];
    __shared__ float s_w[64];
    const int n = blockIdx.x;
    const int tid = threadIdx.x;
    const int start = rowp[n], end = rowp[n + 1];
    float2 acc = {0.f, 0.f};
    for (int base = start; base < end; base += 64) {
        const int m = min(64, end - base);
        if (tid < m) { s_s[tid] = csr_src[base + tid]; s_w[tid] = csr_w[base + tid]; }
        __syncthreads();
        int j = 0;
        for (; j + 1 < m; j += 2) {
            unsigned a0 = hs1u[(size_t)s_s[j] * 64 + tid];
            unsigned a1 = hs1u[(size_t)s_s[j + 1] * 64 + tid];
            float w0 = s_w[j], w1 = s_w[j + 1];
            acc.x = fmaf(bflo(a0), w0, acc.x);
            acc.y = fmaf(bfhi(a0), w0, acc.y);
            acc.x = fmaf(bflo(a1), w1, acc.x);
            acc.y = fmaf(bfhi(a1), w1, acc.y);
        }
        if (j < m) {
            unsigned a0 = hs1u[(size_t)s_s[j] * 64 + tid];
            float w0 = s_w[j];
            acc.x = fmaf(bflo(a0), w0, acc.x);
            acc.y = fmaf(bfhi(a0), w0, acc.y);
        }
        __syncthreads();
    }
    agg1f2[(size_t)n * 64 + tid] = acc;
}

// K6: x = relu((agg1*ndst)@W1+b1);  hs2 = bf16((x*nsrc)@W2)
__global__ __launch_bounds__(128) void k_layer1(const float* __restrict__ agg1,
                                                const float* __restrict__ ndst,
                                                const float* __restrict__ W1,
                                                const float* __restrict__ b1,
                                                const float* __restrict__ nsrc,
                                                const float* __restrict__ W2,
                                                unsigned short* __restrict__ hs2h) {
    __shared__ float a_t[8][WIDTH];
    __shared__ float x_t[8][WIDTH];
    const int row0 = blockIdx.x * 8;
    const int tid = threadIdx.x;
    for (int i = tid; i < 8 * WIDTH; i += 128) {
        int r = i >> 7, k = i & 127;
        a_t[r][k] = agg1[(row0 + r) * WIDTH + k] * ndst[row0 + r];
    }
    __syncthreads();
    float acc[8];
    const float bb = b1[tid];
#pragma unroll
    for (int r = 0; r < 8; ++r) acc[r] = bb;
    for (int k = 0; k < WIDTH; ++k) {
        const float w = W1[k * WIDTH + tid];
#pragma unroll
        for (int r = 0; r < 8; ++r) acc[r] = fmaf(a_t[r][k], w, acc[r]);
    }
#pragma unroll
    for (int r = 0; r < 8; ++r)
        x_t[r][tid] = fmaxf(acc[r], 0.0f) * nsrc[row0 + r];
    __syncthreads();
    const int c2 = tid & 63;
    const int rb = tid >> 6;
    float acc2[4] = {0.f, 0.f, 0.f, 0.f};
    for (int k = 0; k < WIDTH; ++k) {
        const float w = W2[k * F_OUT + c2];
#pragma unroll
        for (int j = 0; j < 4; ++j) acc2[j] = fmaf(x_t[rb + 2 * j][k], w, acc2[j]);
    }
#pragma unroll
    for (int j = 0; j < 4; ++j)
        hs2h[(row0 + rb + 2 * j) * F_OUT + c2] = f2bf(acc2[j]);
}

// K7: agg2[n] = sum_in-edges hs2[src]*w  (1 wave per node, 2 edges/iter)
__global__ __launch_bounds__(64) void k_gather2(const int* __restrict__ rowp,
                                                const int* __restrict__ csr_src,
                                                const float* __restrict__ csr_w,
                                                const unsigned* __restrict__ hs2u,
                                                float2* __restrict__ agg2f2) {
    __shared__ int s_s[64];
    __shared__ float s_w[64];
    const int n = blockIdx.x;
    const int tid = threadIdx.x;
    const int c = tid & 31;
    const int half = tid >> 5;
    const int start = rowp[n], end = rowp[n + 1];
    float2 acc = {0.f, 0.f};
    for (int base = start; base < end; base += 64) {
        const int m = min(64, end - base);
        if (tid < m) { s_s[tid] = csr_src[base + tid]; s_w[tid] = csr_w[base + tid]; }
        __syncthreads();
        int j = 0;
        for (; j + 1 < m; j += 2) {
            int e = j + half;
            unsigned a = hs2u[(size_t)s_s[e] * 32 + c];
            float w = s_w[e];
            acc.x = fmaf(bflo(a), w, acc.x);
            acc.y = fmaf(bfhi(a), w, acc.y);
        }
        if (j < m && half == 0) {
            unsigned a = hs2u[(size_t)s_s[j] * 32 + c];
            float w = s_w[j];
            acc.x = fmaf(bflo(a), w, acc.x);
            acc.y = fmaf(bfhi(a), w, acc.y);
        }
        __syncthreads();
    }
    acc.x += __shfl_xor(acc.x, 32);
    acc.y += __shfl_xor(acc.y, 32);
    if (tid < 32) agg2f2[(size_t)n * 32 + tid] = acc;
}

// K8: per-graph mean pooling via sorted-gid segments
__global__ __launch_bounds__(64) void k_pool(const float* __restrict__ agg2,
                                             const float* __restrict__ ndst,
                                             const float* __restrict__ b2,
                                             const int* __restrict__ gid,
                                             float* __restrict__ out) {
    const int g = blockIdx.x;
    const int t = threadIdx.x;
    int lo = 0, hi = N_NODES;
    while (lo < hi) { int mid = (lo + hi) >> 1; if (gid[mid] < g) lo = mid + 1; else hi = mid; }
    const int start = lo;
    hi = N_NODES;
    while (lo < hi) { int mid = (lo + hi) >> 1; if (gid[mid] < g + 1) lo = mid + 1; else hi = mid; }
    const int end = lo;
    float sum = 0.0f;
    for (int n = start; n < end; ++n)
        sum = fmaf(agg2[n * F_OUT + t], ndst[n], sum);
    out[g * F_OUT + t] = (end > start) ? (sum / (float)(end - start) + b2[t]) : 0.0f;
}

extern "C" void kernel_launch(void* const* d_in, const int* in_sizes, int n_in,
                              void* d_out, int out_size, void* d_ws, size_t ws_size,
                              hipStream_t stream) {
    const float* af  = (const float*)d_in[0];
    const float* bl  = (const float*)d_in[1];
    const int*   src = (const int*)d_in[2];
    const int*   dst = (const int*)d_in[3];
    const int*   gid = (const int*)d_in[4];
    const float* W0  = (const float*)d_in[5];
    const float* b0  = (const float*)d_in[6];
    const float* W1  = (const float*)d_in[7];
    const float* b1  = (const float*)d_in[8];
    const float* W2  = (const float*)d_in[9];
    const float* b2  = (const float*)d_in[10];
    float* out = (float*)d_out;
    float* ws  = (float*)d_ws;

    unsigned* cnt_in  = (unsigned*)(ws + CNT);
    unsigned* dego    = (unsigned*)(ws + DEGO);
    int*      rowp    = (int*)(ws + ROWP);
    int*      bsum    = (int*)(ws + BSUM);
    float*    nsrc    = ws + NSRC;
    float*    ndst    = ws + NDST;
    int*      rank    = (int*)(ws + RANK);
    int*      csr_src = (int*)(ws + CSRS);
    float*    csr_w   = ws + CSRW;
    unsigned short* hs1h = (unsigned short*)(ws + HS1);
    unsigned*       hs1u = (unsigned*)(ws + HS1);
    float*          agg1 = ws + AGG1;
    unsigned short* hs2h = (unsigned short*)(ws + HS2);
    unsigned*       hs2u = (unsigned*)(ws + HS2);
    float*          agg2 = ws + AGG2;

    hipMemsetAsync(d_ws, 0, 100000 * sizeof(float), stream);

    const int EB = (N_EDGES + 255) / 256;
    k_count<<<EB, 256, 0, stream>>>(src, dst, dego, cnt_in, rank);
    k_scanA<<<NBLK_SCAN, 256, 0, stream>>>(cnt_in, rowp, bsum);
    k_scanB<<<1, 256, 0, stream>>>(bsum);
    k_scanC<<<NBLK_SCAN, 256, 0, stream>>>(rowp, bsum, dego, cnt_in, nsrc, ndst);
    k_fill<<<EB, 256, 0, stream>>>(bl, src, dst, rank, rowp, csr_src, csr_w);
    k_embed<<<N_NODES / 8, 128, 0, stream>>>(af, W0, b0, nsrc, hs1h);
    k_gather1<<<N_NODES, 64, 0, stream>>>(rowp, csr_src, csr_w, hs1u, (float2*)agg1);
    k_layer1<<<N_NODES / 8, 128, 0, stream>>>(agg1, ndst, W1, b1, nsrc, W2, hs2h);
    k_gather2<<<N_NODES, 64, 0, stream>>>(rowp, csr_src, csr_w, hs2u, (float2*)agg2);
    k_pool<<<N_GRAPHS, 64, 0, stream>>>(agg2, ndst, b2, gid, out);
}

// Round 5
// 395.422 us; speedup vs baseline: 11.1490x; 1.3303x over previous
//
#include <hip/hip_runtime.h>

#define N_NODES  50000
#define N_EDGES  1600000
#define N_GRAPHS 1000
#define F_IN     92
#define WIDTH    128
#define F_OUT    64
#define NBLK_SCAN 196        // ceil(50000/256)
#define CHUNK    8192        // edges per histogram block (2^13)
#define NBLK_E   196         // ceil(N_EDGES/CHUNK)
#define HPITCH   50048       // u8 histogram row pitch (64-aligned, >= N_NODES)
#define HWORDS   (HPITCH/4)  // 12512 u32 words

// ---- workspace layout (4-byte word offsets) ----
static const size_t CNT  = 0;         // u32[50000] in-degree
static const size_t ROWP = 50000;     // i32[50001]
static const size_t BSUM = 100004;    // i32[256]
static const size_t NSRC = 100260;    // f32[50000]
static const size_t NDST = 150260;    // f32[50000]
static const size_t RNK8 = 200260;    // u8[1.6M] per-edge in-block rank
static const size_t HD   = 600260;    // u8[196][50048] dst hist -> basep (in-place)
static const size_t HSR  = 3052612;   // u8[196][50048] src hist
static const size_t CSR  = 5504964;   // int2[1.6M] (src, w) pairs
static const size_t HS1  = 8704964;   // u32[50000*64] bf16x2-packed
static const size_t AGG1 = 11904964;  // f32[6.4M]
static const size_t HS2  = 18304964;  // u32[50000*32] bf16x2-packed
static const size_t AGG2 = HS1;       // f32[3.2M] aliases HS1 (dead by then)
// total = 19,904,964 words = 79.6 MB

__device__ inline unsigned short f2bf(float f) {
    unsigned u = __float_as_uint(f);
    return (unsigned short)((u + 0x7fff + ((u >> 16) & 1)) >> 16);  // RN
}
__device__ inline float bflo(unsigned u) { return __uint_as_float(u << 16); }
__device__ inline float bfhi(unsigned u) { return __uint_as_float(u & 0xffff0000u); }

// K1: per-block LDS u8 histograms. blocks [0,196): dst (+rank8); [196,392): src.
// Zero global atomics.
__global__ __launch_bounds__(256) void k_hist(const int* __restrict__ src,
                                              const int* __restrict__ dst,
                                              unsigned char* __restrict__ h_dst,
                                              unsigned char* __restrict__ h_src,
                                              unsigned char* __restrict__ rank8) {
    __shared__ unsigned sh[HWORDS];   // 50048 B packed u8 bins
    const bool is_dst = blockIdx.x < NBLK_E;
    const int b = is_dst ? blockIdx.x : blockIdx.x - NBLK_E;
    const int e0 = b * CHUNK;
    const int ecnt = min(CHUNK, N_EDGES - e0);
    for (int i = threadIdx.x; i < HWORDS; i += 256) sh[i] = 0;
    __syncthreads();
    const int* __restrict__ idx = is_dst ? dst : src;
    for (int i = threadIdx.x; i < ecnt; i += 256) {
        int v = idx[e0 + i];
        unsigned sh_amt = (v & 3) * 8;
        unsigned old = atomicAdd(&sh[v >> 2], 1u << sh_amt);
        if (is_dst) rank8[e0 + i] = (unsigned char)((old >> sh_amt) & 0xffu);
    }
    __syncthreads();
    unsigned* out = (unsigned*)((is_dst ? h_dst : h_src) + (size_t)b * HPITCH);
    for (int i = threadIdx.x; i < HWORDS; i += 256) out[i] = sh[i];
}

// K2: column reduce. h_src -> out_deg -> nsrc; h_dst -> in-place exclusive
// prefix over blocks (becomes basep) + total -> cnt_in, ndst.
__global__ __launch_bounds__(256) void k_reduce(unsigned char* __restrict__ h_dst,
                                                const unsigned char* __restrict__ h_src,
                                                unsigned* __restrict__ cnt_in,
                                                float* __restrict__ nsrc,
                                                float* __restrict__ ndst) {
    int n = blockIdx.x * 256 + threadIdx.x;
    if (n >= N_NODES) return;
    unsigned run = 0;
    for (int b = 0; b < NBLK_E; ++b) {
        size_t o = (size_t)b * HPITCH + n;
        unsigned v = h_dst[o];
        h_dst[o] = (unsigned char)run;   // exclusive prefix (max in-deg ~75 < 256)
        run += v;
    }
    cnt_in[n] = run;
    ndst[n] = rsqrtf((float)max(run, 1u));
    unsigned so = 0;
    for (int b = 0; b < NBLK_E; ++b) so += h_src[(size_t)b * HPITCH + n];
    nsrc[n] = rsqrtf((float)max(so, 1u));
}

// K3a: per-block exclusive scan of cnt_in -> rowp + block sums
__global__ __launch_bounds__(256) void k_scanA(const unsigned* __restrict__ cnt_in,
                                               int* __restrict__ rowp,
                                               int* __restrict__ bsum) {
    __shared__ int sd[256];
    const int t = threadIdx.x;
    const int i = blockIdx.x * 256 + t;
    int v = (i < N_NODES) ? (int)cnt_in[i] : 0;
    sd[t] = v;
    __syncthreads();
    for (int off = 1; off < 256; off <<= 1) {
        int add = (t >= off) ? sd[t - off] : 0;
        __syncthreads();
        sd[t] += add;
        __syncthreads();
    }
    if (i < N_NODES) rowp[i] = sd[t] - v;
    if (t == 255) bsum[blockIdx.x] = sd[255];
}

// K3b: exclusive scan of block sums
__global__ __launch_bounds__(256) void k_scanB(int* __restrict__ bsum) {
    __shared__ int sd[256];
    const int t = threadIdx.x;
    int v = (t < NBLK_SCAN) ? bsum[t] : 0;
    sd[t] = v;
    __syncthreads();
    for (int off = 1; off < 256; off <<= 1) {
        int add = (t >= off) ? sd[t - off] : 0;
        __syncthreads();
        sd[t] += add;
        __syncthreads();
    }
    if (t < NBLK_SCAN) bsum[t] = sd[t] - v;
}

// K3c: finalize rowp
__global__ void k_scanC(int* __restrict__ rowp, const int* __restrict__ bsum) {
    int i = blockIdx.x * blockDim.x + threadIdx.x;
    if (i >= N_NODES) return;
    rowp[i] = rowp[i] + bsum[i >> 8];
    if (i == 0) rowp[N_NODES] = N_EDGES;
}

// K4: fill CSR, zero atomics: p = rowp[dst] + basep[chunk][dst] + rank8[e].
// Edge weight folds in nsrc[src] (valid for both layers).
__global__ void k_fill(const float* __restrict__ bl,
                       const int* __restrict__ src, const int* __restrict__ dst,
                       const unsigned char* __restrict__ rank8,
                       const unsigned char* __restrict__ basep,
                       const int* __restrict__ rowp,
                       const float* __restrict__ nsrc,
                       int2* __restrict__ csr) {
    int e = blockIdx.x * blockDim.x + threadIdx.x;
    if (e >= N_EDGES) return;
    float x = bl[3 * e + 0], y = bl[3 * e + 1], z = bl[3 * e + 2];
    int s = src[e], d = dst[e];
    float w = expf(-(x * x + y * y + z * z) * (1.0f / 64.0f)) * nsrc[s];
    int b = e >> 13;   // CHUNK = 8192
    int p = rowp[d] + (int)basep[(size_t)b * HPITCH + d] + (int)rank8[e];
    csr[p] = make_int2(s, __float_as_int(w));
}

// K5: hs1 = bf16(af @ W0 + b0)    [8 rows / 128-thread block]
__global__ __launch_bounds__(128) void k_embed(const float* __restrict__ af,
                                               const float* __restrict__ W0,
                                               const float* __restrict__ b0,
                                               unsigned short* __restrict__ hs1h) {
    __shared__ float tile[8 * F_IN];
    const int row0 = blockIdx.x * 8;
    const int tid = threadIdx.x;
    const float* base = af + row0 * F_IN;
    for (int i = tid; i < 8 * F_IN; i += 128) tile[i] = base[i];
    __syncthreads();
    float acc[8];
    const float bb = b0[tid];
#pragma unroll
    for (int r = 0; r < 8; ++r) acc[r] = bb;
    for (int k = 0; k < F_IN; ++k) {
        const float w = W0[k * WIDTH + tid];
#pragma unroll
        for (int r = 0; r < 8; ++r) acc[r] = fmaf(tile[r * F_IN + k], w, acc[r]);
    }
#pragma unroll
    for (int r = 0; r < 8; ++r)
        hs1h[(row0 + r) * WIDTH + tid] = f2bf(acc[r]);
}

// K6: agg1[n] = sum_in-edges hs1[src]*w   (1 wave per node, bf16x2 per lane)
__global__ __launch_bounds__(64) void k_gather1(const int* __restrict__ rowp,
                                                const int2* __restrict__ csr,
                                                const unsigned* __restrict__ hs1u,
                                                float2* __restrict__ agg1f2) {
    __shared__ int s_s[64];
    __shared__ float s_w[64];
    const int n = blockIdx.x;
    const int tid = threadIdx.x;
    const int start = rowp[n], end = rowp[n + 1];
    float2 acc = {0.f, 0.f};
    for (int base = start; base < end; base += 64) {
        const int m = min(64, end - base);
        if (tid < m) {
            int2 sw = csr[base + tid];
            s_s[tid] = sw.x;
            s_w[tid] = __int_as_float(sw.y);
        }
        __syncthreads();
        int j = 0;
        for (; j + 1 < m; j += 2) {
            unsigned a0 = hs1u[(size_t)s_s[j] * 64 + tid];
            unsigned a1 = hs1u[(size_t)s_s[j + 1] * 64 + tid];
            float w0 = s_w[j], w1 = s_w[j + 1];
            acc.x = fmaf(bflo(a0), w0, acc.x);
            acc.y = fmaf(bfhi(a0), w0, acc.y);
            acc.x = fmaf(bflo(a1), w1, acc.x);
            acc.y = fmaf(bfhi(a1), w1, acc.y);
        }
        if (j < m) {
            unsigned a0 = hs1u[(size_t)s_s[j] * 64 + tid];
            float w0 = s_w[j];
            acc.x = fmaf(bflo(a0), w0, acc.x);
            acc.y = fmaf(bfhi(a0), w0, acc.y);
        }
        __syncthreads();
    }
    agg1f2[(size_t)n * 64 + tid] = acc;
}

// K7: x = relu((agg1*ndst)@W1+b1);  hs2 = bf16(x@W2)
__global__ __launch_bounds__(128) void k_layer1(const float* __restrict__ agg1,
                                                const float* __restrict__ ndst,
                                                const float* __restrict__ W1,
                                                const float* __restrict__ b1,
                                                const float* __restrict__ W2,
                                                unsigned short* __restrict__ hs2h) {
    __shared__ float a_t[8][WIDTH];
    __shared__ float x_t[8][WIDTH];
    const int row0 = blockIdx.x * 8;
    const int tid = threadIdx.x;
    for (int i = tid; i < 8 * WIDTH; i += 128) {
        int r = i >> 7, k = i & 127;
        a_t[r][k] = agg1[(row0 + r) * WIDTH + k] * ndst[row0 + r];
    }
    __syncthreads();
    float acc[8];
    const float bb = b1[tid];
#pragma unroll
    for (int r = 0; r < 8; ++r) acc[r] = bb;
    for (int k = 0; k < WIDTH; ++k) {
        const float w = W1[k * WIDTH + tid];
#pragma unroll
        for (int r = 0; r < 8; ++r) acc[r] = fmaf(a_t[r][k], w, acc[r]);
    }
#pragma unroll
    for (int r = 0; r < 8; ++r)
        x_t[r][tid] = fmaxf(acc[r], 0.0f);
    __syncthreads();
    const int c2 = tid & 63;
    const int rb = tid >> 6;
    float acc2[4] = {0.f, 0.f, 0.f, 0.f};
    for (int k = 0; k < WIDTH; ++k) {
        const float w = W2[k * F_OUT + c2];
#pragma unroll
        for (int j = 0; j < 4; ++j) acc2[j] = fmaf(x_t[rb + 2 * j][k], w, acc2[j]);
    }
#pragma unroll
    for (int j = 0; j < 4; ++j)
        hs2h[(row0 + rb + 2 * j) * F_OUT + c2] = f2bf(acc2[j]);
}

// K8: agg2[n] = sum_in-edges hs2[src]*w  (1 wave per node, 2 edges/iter)
__global__ __launch_bounds__(64) void k_gather2(const int* __restrict__ rowp,
                                                const int2* __restrict__ csr,
                                                const unsigned* __restrict__ hs2u,
                                                float2* __restrict__ agg2f2) {
    __shared__ int s_s[64];
    __shared__ float s_w[64];
    const int n = blockIdx.x;
    const int tid = threadIdx.x;
    const int c = tid & 31;
    const int half = tid >> 5;
    const int start = rowp[n], end = rowp[n + 1];
    float2 acc = {0.f, 0.f};
    for (int base = start; base < end; base += 64) {
        const int m = min(64, end - base);
        if (tid < m) {
            int2 sw = csr[base + tid];
            s_s[tid] = sw.x;
            s_w[tid] = __int_as_float(sw.y);
        }
        __syncthreads();
        int j = 0;
        for (; j + 1 < m; j += 2) {
            int e = j + half;
            unsigned a = hs2u[(size_t)s_s[e] * 32 + c];
            float w = s_w[e];
            acc.x = fmaf(bflo(a), w, acc.x);
            acc.y = fmaf(bfhi(a), w, acc.y);
        }
        if (j < m && half == 0) {
            unsigned a = hs2u[(size_t)s_s[j] * 32 + c];
            float w = s_w[j];
            acc.x = fmaf(bflo(a), w, acc.x);
            acc.y = fmaf(bfhi(a), w, acc.y);
        }
        __syncthreads();
    }
    acc.x += __shfl_xor(acc.x, 32);
    acc.y += __shfl_xor(acc.y, 32);
    if (tid < 32) agg2f2[(size_t)n * 32 + tid] = acc;
}

// K9: per-graph mean pooling via sorted-gid segments
__global__ __launch_bounds__(64) void k_pool(const float* __restrict__ agg2,
                                             const float* __restrict__ ndst,
                                             const float* __restrict__ b2,
                                             const int* __restrict__ gid,
                                             float* __restrict__ out) {
    const int g = blockIdx.x;
    const int t = threadIdx.x;
    int lo = 0, hi = N_NODES;
    while (lo < hi) { int mid = (lo + hi) >> 1; if (gid[mid] < g) lo = mid + 1; else hi = mid; }
    const int start = lo;
    hi = N_NODES;
    while (lo < hi) { int mid = (lo + hi) >> 1; if (gid[mid] < g + 1) lo = mid + 1; else hi = mid; }
    const int end = lo;
    float sum = 0.0f;
    for (int n = start; n < end; ++n)
        sum = fmaf(agg2[n * F_OUT + t], ndst[n], sum);
    out[g * F_OUT + t] = (end > start) ? (sum / (float)(end - start) + b2[t]) : 0.0f;
}

extern "C" void kernel_launch(void* const* d_in, const int* in_sizes, int n_in,
                              void* d_out, int out_size, void* d_ws, size_t ws_size,
                              hipStream_t stream) {
    const float* af  = (const float*)d_in[0];
    const float* bl  = (const float*)d_in[1];
    const int*   src = (const int*)d_in[2];
    const int*   dst = (const int*)d_in[3];
    const int*   gid = (const int*)d_in[4];
    const float* W0  = (const float*)d_in[5];
    const float* b0  = (const float*)d_in[6];
    const float* W1  = (const float*)d_in[7];
    const float* b1  = (const float*)d_in[8];
    const float* W2  = (const float*)d_in[9];
    const float* b2  = (const float*)d_in[10];
    float* out = (float*)d_out;
    float* ws  = (float*)d_ws;

    unsigned*       cnt_in = (unsigned*)(ws + CNT);
    int*            rowp   = (int*)(ws + ROWP);
    int*            bsum   = (int*)(ws + BSUM);
    float*          nsrc   = ws + NSRC;
    float*          ndst   = ws + NDST;
    unsigned char*  rank8  = (unsigned char*)(ws + RNK8);
    unsigned char*  h_dst  = (unsigned char*)(ws + HD);
    unsigned char*  h_src  = (unsigned char*)(ws + HSR);
    int2*           csr    = (int2*)(ws + CSR);
    unsigned short* hs1h   = (unsigned short*)(ws + HS1);
    unsigned*       hs1u   = (unsigned*)(ws + HS1);
    float*          agg1   = ws + AGG1;
    unsigned short* hs2h   = (unsigned short*)(ws + HS2);
    unsigned*       hs2u   = (unsigned*)(ws + HS2);
    float*          agg2   = ws + AGG2;

    const int EB = (N_EDGES + 255) / 256;
    k_hist<<<2 * NBLK_E, 256, 0, stream>>>(src, dst, h_dst, h_src, rank8);
    k_reduce<<<NBLK_SCAN, 256, 0, stream>>>(h_dst, h_src, cnt_in, nsrc, ndst);
    k_scanA<<<NBLK_SCAN, 256, 0, stream>>>(cnt_in, rowp, bsum);
    k_scanB<<<1, 256, 0, stream>>>(bsum);
    k_scanC<<<NBLK_SCAN, 256, 0, stream>>>(rowp, bsum);
    k_fill<<<EB, 256, 0, stream>>>(bl, src, dst, rank8, h_dst, rowp, nsrc, csr);
    k_embed<<<N_NODES / 8, 128, 0, stream>>>(af, W0, b0, hs1h);
    k_gather1<<<N_NODES, 64, 0, stream>>>(rowp, csr, hs1u, (float2*)agg1);
    k_layer1<<<N_NODES / 8, 128, 0, stream>>>(agg1, ndst, W1, b1, W2, hs2h);
    k_gather2<<<N_NODES, 64, 0, stream>>>(rowp, csr, hs2u, (float2*)agg2);
    k_pool<<<N_GRAPHS, 64, 0, stream>>>(agg2, ndst, b2, gid, out);
}